// Round 2
// baseline (66.491 us; speedup 1.0000x reference)
//
#include <hip/hip_runtime.h>
#include <hip/hip_bf16.h>

// SimpleQNN closed form (derivation verified by hand, round 1):
//   z[b][w]   = cos(rx[w]) * sin(x[b][w] - ry[w])
//   q[b][0]   = prod_{w=1..15} z[b][w]          (mask S_0 = {1..15})
//   q[b][j]   = prod_{w=0..j}  z[b][w], j>=1    (mask S_j = {0..j})
//   out[b][k] = bias[k] + sum_j q[b][j] * W[k][j]
//
// Why: layers RY(x),H,RY(ry),RX(rx) keep a product state over |0...0>;
// per-wire Z-expectation algebra gives z_w = cos(rx)*sin(x - ry).
// CRZ/CZ/RZ are diagonal unit-modulus -> no effect on probabilities.
// CNOT ring (ctrl w -> tgt (w+1)%16, w=0..15 sequential) maps bits
// a -> (a0^s15, s1, s2, ..., s15) with s_j = a0^...^aj, so measured
// parities are prefix XORs -> expectations factor into prefix products.
// rz_params / crz_params provably do not affect the output.
//
// Dtypes: all float32, per the reference (round-1 NaN proved inputs are
// NOT bf16: bf16-misreading float32 data decodes stray NaNs).

#define NW 16
#define NB 64
#define NO 10

__global__ __launch_bounds__(64) void SimpleQNN_kernel(
    const float* __restrict__ x,     // (64,16)
    const float* __restrict__ ry,    // (16)
    const float* __restrict__ rx,    // (16)
    const float* __restrict__ W,     // (10,16)
    const float* __restrict__ bias,  // (10)
    float* __restrict__ out)         // (64,10)
{
    const int b = threadIdx.x;  // one batch row per lane; single wave
    if (b >= NB) return;

    float z[NW];
#pragma unroll
    for (int w = 0; w < NW; ++w) {
        z[w] = __cosf(0.0f + rx[w]) * sinf(x[b * NW + w] - ry[w]);
    }

    float q[NW];
    // q[0] = suffix product z1..z15 (no division: z[0] may be ~0)
    float p0 = 1.0f;
#pragma unroll
    for (int w = 1; w < NW; ++w) p0 *= z[w];
    q[0] = p0;
    // q[j] = prefix product z0..zj
    float p = z[0];
#pragma unroll
    for (int w = 1; w < NW; ++w) { p *= z[w]; q[w] = p; }

#pragma unroll
    for (int k = 0; k < NO; ++k) {
        float acc = bias[k];
#pragma unroll
        for (int j = 0; j < NW; ++j) acc = fmaf(q[j], W[k * NW + j], acc);
        out[b * NO + k] = acc;
    }
}

extern "C" void kernel_launch(void* const* d_in, const int* in_sizes, int n_in,
                              void* d_out, int out_size, void* d_ws, size_t ws_size,
                              hipStream_t stream) {
    // setup_inputs order: x, ry_params, rx_params, rz_params, crz_params, W, b
    const float* x    = (const float*)d_in[0];
    const float* ry   = (const float*)d_in[1];
    const float* rx   = (const float*)d_in[2];
    // d_in[3] = rz_params, d_in[4] = crz_params: unused (diagonal phases only)
    const float* W    = (const float*)d_in[5];
    const float* bias = (const float*)d_in[6];
    float* out = (float*)d_out;

    SimpleQNN_kernel<<<1, 64, 0, stream>>>(x, ry, rx, W, bias, out);
}